// Round 10
// baseline (190.873 us; speedup 1.0000x reference)
//
#include <hip/hip_runtime.h>

#define IN_DIM 64
#define OUT_DIM 16
#define NGRID 12      // (NUM+1) + 2*K
#define NB 8          // NUM + K
#define TST 68        // transpose buffer row stride (floats), 2-way banks max
#define ROWS 8        // batch rows per wave

typedef _Float16 half2_t __attribute__((ext_vector_type(2)));
typedef float    fx4     __attribute__((ext_vector_type(4)));

__device__ __forceinline__ half2_t pkrtz(float a, float b) {
    return __builtin_bit_cast(half2_t, __builtin_amdgcn_cvt_pkrtz(a, b));
}

__device__ __forceinline__ float dpp_add16(float v) {
    // sum across each 16-lane DPP row; row_shr accumulates toward higher
    // lanes -> full row sum lands in lane 15 of each row
    int x = __builtin_bit_cast(int, v);
    v += __builtin_bit_cast(float, __builtin_amdgcn_update_dpp(0, x, 0x118, 0xf, 0xf, true)); // row_shr:8
    x = __builtin_bit_cast(int, v);
    v += __builtin_bit_cast(float, __builtin_amdgcn_update_dpp(0, x, 0x114, 0xf, 0xf, true)); // row_shr:4
    x = __builtin_bit_cast(int, v);
    v += __builtin_bit_cast(float, __builtin_amdgcn_update_dpp(0, x, 0x112, 0xf, 0xf, true)); // row_shr:2
    x = __builtin_bit_cast(int, v);
    v += __builtin_bit_cast(float, __builtin_amdgcn_update_dpp(0, x, 0x111, 0xf, 0xf, true)); // row_shr:1
    return v;
}

// Shared spline-basis computation (uniform extended grid, t-space)
__device__ __forceinline__ void spline_basis(float t, half2_t bh[4]) {
    float d[NGRID];
    #pragma unroll
    for (int j = 0; j < NGRID; ++j) d[j] = t - (float)j;

    float Bv[11];
    #pragma unroll
    for (int j = 0; j < 11; ++j)
        Bv[j] = (d[j] >= 0.0f && d[j + 1] < 0.0f) ? 1.0f : 0.0f;

    #pragma unroll
    for (int j = 0; j < 10; ++j)
        Bv[j] = d[j] * Bv[j] - d[j + 2] * Bv[j + 1];                       // p=1
    #pragma unroll
    for (int j = 0; j < 9; ++j)
        Bv[j] = (d[j] * Bv[j] - d[j + 3] * Bv[j + 1]) * 0.5f;              // p=2
    #pragma unroll
    for (int j = 0; j < 8; ++j)
        Bv[j] = (d[j] * Bv[j] - d[j + 4] * Bv[j + 1]) * (1.0f / 3.0f);     // p=3

    #pragma unroll
    for (int q = 0; q < 4; ++q)
        bh[q] = pkrtz(Bv[2 * q], Bv[2 * q + 1]);
}

// ---------------- K1: postspline only (single 268 MB NT stream) ----------------
__global__ __launch_bounds__(256, 3) void kan_spline_kernel(
    const float* __restrict__ x, const float* __restrict__ grid,
    const float* __restrict__ coef, float* __restrict__ postspline, int batch)
{
    __shared__ float sT[4][OUT_DIM * TST];
    const int tid = threadIdx.x, lane = tid & 63, wave = tid >> 6, i = lane;
    const long b0 = ((long)blockIdx.x * 4 + wave) * ROWS;
    if (b0 >= batch) return;

    const float g0 = grid[i * NGRID + 0];
    const float invh = 1.0f / (grid[i * NGRID + 1] - g0);

    half2_t c[OUT_DIM][4];
    {
        const fx4* c4 = reinterpret_cast<const fx4*>(coef + (size_t)i * OUT_DIM * NB);
        #pragma unroll
        for (int o = 0; o < OUT_DIM; ++o) {
            fx4 a = c4[o * 2], bq = c4[o * 2 + 1];
            c[o][0] = pkrtz(a.x, a.y);  c[o][1] = pkrtz(a.z, a.w);
            c[o][2] = pkrtz(bq.x, bq.y); c[o][3] = pkrtz(bq.z, bq.w);
        }
    }

    const int ci = (lane & 15) * 4;
    const int ro = lane >> 4;
    float* sTw = sT[wave];
    float xi_cur = x[b0 * IN_DIM + i];

    #pragma unroll 1
    for (int r = 0; r < ROWS; ++r) {
        const long b = b0 + r;
        float xi_next = 0.0f;
        if (r + 1 < ROWS && b + 1 < batch) xi_next = x[(b + 1) * IN_DIM + i];
        const float t = (xi_cur - g0) * invh;

        half2_t bh[4];
        spline_basis(t, bh);

        #pragma unroll
        for (int o = 0; o < OUT_DIM; ++o) {
            float y = __builtin_amdgcn_fdot2(c[o][0], bh[0],
                      __builtin_amdgcn_fdot2(c[o][1], bh[1],
                      __builtin_amdgcn_fdot2(c[o][2], bh[2],
                      __builtin_amdgcn_fdot2(c[o][3], bh[3], 0.0f, false),
                      false), false), false);
            sTw[o * TST + i] = y;
        }

        const size_t rowoff = (size_t)b * (OUT_DIM * IN_DIM);
        #pragma unroll
        for (int sl = 0; sl < 4; ++sl) {
            const int row = sl * 4 + ro;
            fx4 yv = *reinterpret_cast<const fx4*>(&sTw[row * TST + ci]);
            __builtin_nontemporal_store(yv,
                reinterpret_cast<fx4*>(&postspline[rowoff + (size_t)sl * 256 + 4 * lane]));
        }
        xi_cur = xi_next;
    }
}

// ---------------- K2: postacts + out (single 268 MB NT stream + 4 MB) ----------------
__global__ __launch_bounds__(256, 3) void kan_acts_kernel(
    const float* __restrict__ x, const float* __restrict__ grid,
    const float* __restrict__ coef, const float* __restrict__ sbase,
    const float* __restrict__ ssp, float* __restrict__ out,
    float* __restrict__ postacts, int batch)
{
    __shared__ float sT[4][OUT_DIM * TST];
    const int tid = threadIdx.x, lane = tid & 63, wave = tid >> 6, i = lane;
    const long b0 = ((long)blockIdx.x * 4 + wave) * ROWS;
    if (b0 >= batch) return;

    const float g0 = grid[i * NGRID + 0];
    const float invh = 1.0f / (grid[i * NGRID + 1] - g0);

    half2_t c[OUT_DIM][4];
    {
        const fx4* c4 = reinterpret_cast<const fx4*>(coef + (size_t)i * OUT_DIM * NB);
        #pragma unroll
        for (int o = 0; o < OUT_DIM; ++o) {
            fx4 a = c4[o * 2], bq = c4[o * 2 + 1];
            c[o][0] = pkrtz(a.x, a.y);  c[o][1] = pkrtz(a.z, a.w);
            c[o][2] = pkrtz(bq.x, bq.y); c[o][3] = pkrtz(bq.z, bq.w);
        }
    }

    const int ci = (lane & 15) * 4;
    const int ro = lane >> 4;
    float sbt[4][4], spt[4][4];
    #pragma unroll
    for (int sl = 0; sl < 4; ++sl) {
        const int o = sl * 4 + ro;
        #pragma unroll
        for (int k = 0; k < 4; ++k) {
            sbt[sl][k] = sbase[(ci + k) * OUT_DIM + o];
            spt[sl][k] = ssp  [(ci + k) * OUT_DIM + o];
        }
    }

    float* sTw = sT[wave];
    float xi_cur = x[b0 * IN_DIM + i];

    #pragma unroll 1
    for (int r = 0; r < ROWS; ++r) {
        const long b = b0 + r;
        float xi_next = 0.0f;
        if (r + 1 < ROWS && b + 1 < batch) xi_next = x[(b + 1) * IN_DIM + i];
        const float xi = xi_cur;
        const float t = (xi - g0) * invh;

        half2_t bh[4];
        spline_basis(t, bh);

        #pragma unroll
        for (int o = 0; o < OUT_DIM; ++o) {
            float y = __builtin_amdgcn_fdot2(c[o][0], bh[0],
                      __builtin_amdgcn_fdot2(c[o][1], bh[1],
                      __builtin_amdgcn_fdot2(c[o][2], bh[2],
                      __builtin_amdgcn_fdot2(c[o][3], bh[3], 0.0f, false),
                      false), false), false);
            sTw[o * TST + i] = y;
        }

        const float base = xi / (1.0f + __expf(-xi));
        fx4 bq;
        bq.x = __shfl(base, ci + 0, 64);
        bq.y = __shfl(base, ci + 1, 64);
        bq.z = __shfl(base, ci + 2, 64);
        bq.w = __shfl(base, ci + 3, 64);

        const size_t rowoff = (size_t)b * (OUT_DIM * IN_DIM);
        float ps0, ps1, ps2, ps3;

        #pragma unroll
        for (int sl = 0; sl < 4; ++sl) {
            const int row = sl * 4 + ro;
            fx4 yv = *reinterpret_cast<const fx4*>(&sTw[row * TST + ci]);
            fx4 y2;
            y2.x = __builtin_fmaf(sbt[sl][0], bq.x, spt[sl][0] * yv.x);
            y2.y = __builtin_fmaf(sbt[sl][1], bq.y, spt[sl][1] * yv.y);
            y2.z = __builtin_fmaf(sbt[sl][2], bq.z, spt[sl][2] * yv.z);
            y2.w = __builtin_fmaf(sbt[sl][3], bq.w, spt[sl][3] * yv.w);

            __builtin_nontemporal_store(y2,
                reinterpret_cast<fx4*>(&postacts[rowoff + (size_t)sl * 256 + 4 * lane]));

            const float ps = (y2.x + y2.y) + (y2.z + y2.w);
            if (sl == 0) ps0 = ps; else if (sl == 1) ps1 = ps;
            else if (sl == 2) ps2 = ps; else ps3 = ps;
        }

        ps0 = dpp_add16(ps0);
        ps1 = dpp_add16(ps1);
        ps2 = dpp_add16(ps2);
        ps3 = dpp_add16(ps3);
        if ((lane & 15) == 15) {
            float* ob = out + (size_t)b * OUT_DIM;
            ob[0  + ro] = ps0;
            ob[4  + ro] = ps1;
            ob[8  + ro] = ps2;
            ob[12 + ro] = ps3;
        }
        xi_cur = xi_next;
    }
}

// ---------------- K3: preacts broadcast fill (single 268 MB NT stream) ----------------
// lane l covers o = q*4 + l/16, col = l%16  ->  each store instr = 1 KB contiguous
__global__ __launch_bounds__(256) void kan_pre_kernel(
    const float* __restrict__ x, float* __restrict__ preacts, int batch)
{
    const int lane = threadIdx.x & 63;
    const int wave = threadIdx.x >> 6;
    const long b0 = ((long)blockIdx.x * 4 + wave) * 16;
    if (b0 >= batch) return;
    const fx4* __restrict__ xv = reinterpret_cast<const fx4*>(x);
    fx4* __restrict__ pa = reinterpret_cast<fx4*>(preacts);
    const int col = lane & 15;

    fx4 v = xv[b0 * 16 + col];
    #pragma unroll 1
    for (int r = 0; r < 16; ++r) {
        const long b = b0 + r;
        fx4 vn = v;
        if (r + 1 < 16 && b + 1 < batch) vn = xv[(b + 1) * 16 + col];
        const long base = b * 256;
        __builtin_nontemporal_store(v, &pa[base +   0 + lane]);
        __builtin_nontemporal_store(v, &pa[base +  64 + lane]);
        __builtin_nontemporal_store(v, &pa[base + 128 + lane]);
        __builtin_nontemporal_store(v, &pa[base + 192 + lane]);
        v = vn;
    }
}

extern "C" void kernel_launch(void* const* d_in, const int* in_sizes, int n_in,
                              void* d_out, int out_size, void* d_ws, size_t ws_size,
                              hipStream_t stream) {
    const float* x     = (const float*)d_in[0];
    const float* grid  = (const float*)d_in[1];
    const float* coef  = (const float*)d_in[2];
    const float* sbase = (const float*)d_in[3];
    const float* ssp   = (const float*)d_in[4];

    const int batch = in_sizes[0] / IN_DIM;

    float* out = (float*)d_out;
    float* preacts    = out + (size_t)batch * OUT_DIM;
    float* postacts   = preacts  + (size_t)batch * OUT_DIM * IN_DIM;
    float* postspline = postacts + (size_t)batch * OUT_DIM * IN_DIM;

    const int nb_main = (batch + 4 * ROWS - 1) / (4 * ROWS);   // 2048
    const int nb_pre  = (batch + 4 * 16 - 1) / (4 * 16);       // 1024

    kan_spline_kernel<<<nb_main, 256, 0, stream>>>(x, grid, coef, postspline, batch);
    kan_acts_kernel  <<<nb_main, 256, 0, stream>>>(x, grid, coef, sbase, ssp, out, postacts, batch);
    kan_pre_kernel   <<<nb_pre,  256, 0, stream>>>(x, preacts, batch);
}

// Round 11
// 163.077 us; speedup vs baseline: 1.1704x; 1.1704x over previous
//
#include <hip/hip_runtime.h>

#define IN_DIM 64
#define OUT_DIM 16
#define NGRID 12      // (NUM+1) + 2*K
#define NB 8          // NUM + K
#define ROWS 8        // batch rows per wave

typedef _Float16 half2_t __attribute__((ext_vector_type(2)));
typedef float    fx4     __attribute__((ext_vector_type(4)));

__device__ __forceinline__ half2_t pkrtz(float a, float b) {
    return __builtin_bit_cast(half2_t, __builtin_amdgcn_cvt_pkrtz(a, b));
}

__device__ __forceinline__ float dpp_add16(float v) {
    // sum across each 16-lane DPP row; row_shr accumulates toward higher
    // lanes -> full row sum lands in lane 15 of each row
    int x = __builtin_bit_cast(int, v);
    v += __builtin_bit_cast(float, __builtin_amdgcn_update_dpp(0, x, 0x118, 0xf, 0xf, true)); // row_shr:8
    x = __builtin_bit_cast(int, v);
    v += __builtin_bit_cast(float, __builtin_amdgcn_update_dpp(0, x, 0x114, 0xf, 0xf, true)); // row_shr:4
    x = __builtin_bit_cast(int, v);
    v += __builtin_bit_cast(float, __builtin_amdgcn_update_dpp(0, x, 0x112, 0xf, 0xf, true)); // row_shr:2
    x = __builtin_bit_cast(int, v);
    v += __builtin_bit_cast(float, __builtin_amdgcn_update_dpp(0, x, 0x111, 0xf, 0xf, true)); // row_shr:1
    return v;
}

// basis for one scalar t (uniform knots, t-space); emits 4 packed f16 pairs
__device__ __forceinline__ void spline_basis(float t, half2_t bh[4]) {
    float d[NGRID];
    #pragma unroll
    for (int j = 0; j < NGRID; ++j) d[j] = t - (float)j;

    float Bv[11];
    #pragma unroll
    for (int j = 0; j < 11; ++j)
        Bv[j] = (d[j] >= 0.0f && d[j + 1] < 0.0f) ? 1.0f : 0.0f;

    #pragma unroll
    for (int j = 0; j < 10; ++j)
        Bv[j] = d[j] * Bv[j] - d[j + 2] * Bv[j + 1];                       // p=1
    #pragma unroll
    for (int j = 0; j < 9; ++j)
        Bv[j] = (d[j] * Bv[j] - d[j + 3] * Bv[j + 1]) * 0.5f;              // p=2
    #pragma unroll
    for (int j = 0; j < 8; ++j)
        Bv[j] = (d[j] * Bv[j] - d[j + 4] * Bv[j + 1]) * (1.0f / 3.0f);     // p=3

    #pragma unroll
    for (int q = 0; q < 4; ++q)
        bh[q] = pkrtz(Bv[2 * q], Bv[2 * q + 1]);
}

// Zero-LDS layout: lane owns i = ci..ci+3 (ci=(lane&15)*4) and o = sl*4+ro
// (ro=lane>>4, sl=0..3). Every output fx4 is produced in-register; no LDS,
// no shuffles. Store offset rowoff + (sl*4+ro)*64 + ci == R6's 4*lane form.
__global__ __launch_bounds__(256, 3) void kan_fwd_kernel(
    const float* __restrict__ x,      // [B,64]
    const float* __restrict__ grid,   // [64,12]
    const float* __restrict__ coef,   // [64,16,8]
    const float* __restrict__ sbase,  // [64,16]
    const float* __restrict__ ssp,    // [64,16]
    float* __restrict__ out,          // [B,16]
    float* __restrict__ preacts,      // [B,16,64]
    float* __restrict__ postacts,     // [B,16,64]
    float* __restrict__ postspline,   // [B,16,64]
    int batch)
{
    const int tid  = threadIdx.x;
    const int lane = tid & 63;
    const int wave = tid >> 6;
    const int ci = (lane & 15) * 4;   // base of the 4 input dims this lane owns
    const int ro = lane >> 4;         // output-dim offset within each slice

    const long b0 = ((long)blockIdx.x * 4 + wave) * ROWS;
    if (b0 >= batch) return;

    // per-owned-i uniform-grid parameters
    float g0v[4], invhv[4];
    #pragma unroll
    for (int k = 0; k < 4; ++k) {
        const float a0 = grid[(ci + k) * NGRID + 0];
        const float a1 = grid[(ci + k) * NGRID + 1];
        g0v[k] = a0;
        invhv[k] = 1.0f / (a1 - a0);
    }

    // coef -> packed f16: c[k][sl][q] for (i=ci+k, o=sl*4+ro), 64 VGPRs total
    half2_t c[4][4][4];
    #pragma unroll
    for (int k = 0; k < 4; ++k) {
        const fx4* c4 = reinterpret_cast<const fx4*>(coef + (size_t)(ci + k) * OUT_DIM * NB);
        #pragma unroll
        for (int sl = 0; sl < 4; ++sl) {
            const int o = sl * 4 + ro;
            fx4 a = c4[o * 2], bq = c4[o * 2 + 1];
            c[k][sl][0] = pkrtz(a.x,  a.y);
            c[k][sl][1] = pkrtz(a.z,  a.w);
            c[k][sl][2] = pkrtz(bq.x, bq.y);
            c[k][sl][3] = pkrtz(bq.z, bq.w);
        }
    }

    // scales packed half2(sbase, ssp): s2[k][sl], 16 VGPRs
    half2_t s2[4][4];
    #pragma unroll
    for (int k = 0; k < 4; ++k)
        #pragma unroll
        for (int sl = 0; sl < 4; ++sl) {
            const int o = sl * 4 + ro;
            s2[k][sl] = pkrtz(sbase[(ci + k) * OUT_DIM + o],
                              ssp  [(ci + k) * OUT_DIM + o]);
        }

    const fx4* __restrict__ xv4 = reinterpret_cast<const fx4*>(x);
    fx4 xv = xv4[b0 * 16 + (lane & 15)];

    #pragma unroll 1
    for (int r = 0; r < ROWS; ++r) {
        const long b = b0 + r;
        if (b >= batch) break;
        fx4 xv_next = xv;
        if (r + 1 < ROWS && b + 1 < batch) xv_next = xv4[(b + 1) * 16 + (lane & 15)];

        // basis + silu for the 4 owned input dims (4 independent chains -> ILP)
        half2_t bh[4][4];
        fx4 silu4;
        #pragma unroll
        for (int k = 0; k < 4; ++k) {
            const float xk = xv[k];
            spline_basis((xk - g0v[k]) * invhv[k], bh[k]);
            silu4[k] = xk / (1.0f + __expf(-xk));
        }

        const size_t rowoff = (size_t)b * (OUT_DIM * IN_DIM);
        float ps0, ps1, ps2, ps3;

        #pragma unroll
        for (int sl = 0; sl < 4; ++sl) {
            fx4 yv, y2v;
            #pragma unroll
            for (int k = 0; k < 4; ++k) {
                float y = __builtin_amdgcn_fdot2(c[k][sl][0], bh[k][0],
                          __builtin_amdgcn_fdot2(c[k][sl][1], bh[k][1],
                          __builtin_amdgcn_fdot2(c[k][sl][2], bh[k][2],
                          __builtin_amdgcn_fdot2(c[k][sl][3], bh[k][3], 0.0f, false),
                          false), false), false);
                yv[k]  = y;
                y2v[k] = __builtin_amdgcn_fdot2(s2[k][sl], pkrtz(silu4[k], y), 0.0f, false);
            }

            const size_t goff = rowoff + (size_t)sl * 256 + 4 * lane;
            __builtin_nontemporal_store(yv,  reinterpret_cast<fx4*>(&postspline[goff]));
            __builtin_nontemporal_store(y2v, reinterpret_cast<fx4*>(&postacts[goff]));
            __builtin_nontemporal_store(xv,  reinterpret_cast<fx4*>(&preacts[goff]));

            const float ps = (y2v.x + y2v.y) + (y2v.z + y2v.w);
            if (sl == 0) ps0 = ps; else if (sl == 1) ps1 = ps;
            else if (sl == 2) ps2 = ps; else ps3 = ps;
        }

        // out[b, o]: DPP reduction across each 16-lane row; sum lands in lane 15
        ps0 = dpp_add16(ps0);
        ps1 = dpp_add16(ps1);
        ps2 = dpp_add16(ps2);
        ps3 = dpp_add16(ps3);
        if ((lane & 15) == 15) {
            float* ob = out + (size_t)b * OUT_DIM;
            ob[0  + ro] = ps0;
            ob[4  + ro] = ps1;
            ob[8  + ro] = ps2;
            ob[12 + ro] = ps3;
        }

        xv = xv_next;
    }
}

extern "C" void kernel_launch(void* const* d_in, const int* in_sizes, int n_in,
                              void* d_out, int out_size, void* d_ws, size_t ws_size,
                              hipStream_t stream) {
    const float* x     = (const float*)d_in[0];
    const float* grid  = (const float*)d_in[1];
    const float* coef  = (const float*)d_in[2];
    const float* sbase = (const float*)d_in[3];
    const float* ssp   = (const float*)d_in[4];

    const int batch = in_sizes[0] / IN_DIM;

    float* out = (float*)d_out;
    float* preacts    = out + (size_t)batch * OUT_DIM;
    float* postacts   = preacts  + (size_t)batch * OUT_DIM * IN_DIM;
    float* postspline = postacts + (size_t)batch * OUT_DIM * IN_DIM;

    const int rows_per_block = 4 * ROWS;     // 4 waves x 8 rows
    const int nblocks = (batch + rows_per_block - 1) / rows_per_block;
    kan_fwd_kernel<<<nblocks, 256, 0, stream>>>(
        x, grid, coef, sbase, ssp, out, preacts, postacts, postspline, batch);
}